// Round 1
// 1128.772 us; speedup vs baseline: 2.0023x; 2.0023x over previous
//
#include <hip/hip_runtime.h>
#include <hip/hip_bf16.h>

#define B_   8
#define C_   512
#define H_   128
#define W_   128
#define CQ_  64
#define BH_  (B_ * H_)
#define HW_  (H_ * W_)

typedef __bf16 bf16x8 __attribute__((ext_vector_type(8)));
typedef __bf16 bf16x4 __attribute__((ext_vector_type(4)));
typedef float  f32x4  __attribute__((ext_vector_type(4)));

// ---------------------------------------------------------------------------
// K1: q,k conv1x1.  grid = BH (1024), block = 256.  (unchanged)
// ---------------------------------------------------------------------------
__global__ __launch_bounds__(256) void qk_kernel(
    const float* __restrict__ x, const float* __restrict__ Wq,
    const float* __restrict__ bq, const float* __restrict__ Wk,
    const float* __restrict__ bk, float* __restrict__ qout,
    float* __restrict__ kout) {
  __shared__ __align__(16) float xs[32 * 128];   // [cc][w]
  __shared__ float wqs[64 * 33];                 // [o][cc] pad 33
  __shared__ float wks[64 * 33];
  const int t  = threadIdx.x;
  const int bh = blockIdx.x;
  const int b  = bh >> 7, h = bh & 127;
  const int wg = t & 7, og = t >> 3;             // wg: w-group (16 w), og: o-pair
  const float* xbase = x + (size_t)b * C_ * HW_ + (size_t)h * W_;

  float qa0[16], qa1[16], ka0[16], ka1[16];
#pragma unroll
  for (int m = 0; m < 16; ++m) { qa0[m] = 0.f; qa1[m] = 0.f; ka0[m] = 0.f; ka1[m] = 0.f; }

  for (int ctile = 0; ctile < 16; ++ctile) {
    const int cbase = ctile * 32;
    __syncthreads();
#pragma unroll
    for (int s = 0; s < 16; ++s) {
      int e = t + s * 256; int cc = e >> 7, w = e & 127;
      xs[e] = xbase[(size_t)(cbase + cc) * HW_ + w];
    }
#pragma unroll
    for (int s = 0; s < 8; ++s) {
      int e = t + s * 256; int o = e >> 5, cc = e & 31;
      wqs[o * 33 + cc] = Wq[o * C_ + cbase + cc];
      wks[o * 33 + cc] = Wk[o * C_ + cbase + cc];
    }
    __syncthreads();
#pragma unroll 8
    for (int cc = 0; cc < 32; ++cc) {
      const float4* xr = (const float4*)(xs + cc * 128 + wg * 16);
      float xv[16];
      *(float4*)&xv[0]  = xr[0];
      *(float4*)&xv[4]  = xr[1];
      *(float4*)&xv[8]  = xr[2];
      *(float4*)&xv[12] = xr[3];
      const float wq0 = wqs[(og * 2 + 0) * 33 + cc];
      const float wq1 = wqs[(og * 2 + 1) * 33 + cc];
      const float wk0 = wks[(og * 2 + 0) * 33 + cc];
      const float wk1 = wks[(og * 2 + 1) * 33 + cc];
#pragma unroll
      for (int m = 0; m < 16; ++m) {
        qa0[m] = fmaf(wq0, xv[m], qa0[m]);
        qa1[m] = fmaf(wq1, xv[m], qa1[m]);
        ka0[m] = fmaf(wk0, xv[m], ka0[m]);
        ka1[m] = fmaf(wk1, xv[m], ka1[m]);
      }
    }
  }

  const int o0 = og * 2, o1 = og * 2 + 1;
  const float bq0 = bq[o0], bq1 = bq[o1], bk0 = bk[o0], bk1 = bk[o1];
  float* q0 = qout + (size_t)bh * CQ_ * W_ + o0 * W_ + wg * 16;
  float* q1 = qout + (size_t)bh * CQ_ * W_ + o1 * W_ + wg * 16;
  float* k0 = kout + (size_t)bh * CQ_ * W_ + o0 * W_ + wg * 16;
  float* k1 = kout + (size_t)bh * CQ_ * W_ + o1 * W_ + wg * 16;
#pragma unroll
  for (int m = 0; m < 16; ++m) {
    q0[m] = qa0[m] + bq0;
    q1[m] = qa1[m] + bq1;
    k0[m] = ka0[m] + bk0;
    k1[m] = ka1[m] + bk1;
  }
}

// ---------------------------------------------------------------------------
// K2: energy + softmax.  grid = BH, block = 256.  (unchanged)
// ---------------------------------------------------------------------------
__global__ __launch_bounds__(256) void attn_kernel(
    const float* __restrict__ qin, const float* __restrict__ kin,
    float* __restrict__ attn) {
  __shared__ float qs[64 * 128];   // [cq][w]
  __shared__ float kts[128 * 64];  // [w][cq] (transposed)
  const int t  = threadIdx.x;
  const int bh = blockIdx.x;
  const int lane = t & 63, wv = t >> 6;
  const float* qb = qin + (size_t)bh * 8192;
  const float* kb = kin + (size_t)bh * 8192;
#pragma unroll
  for (int s = 0; s < 32; ++s) {
    int e = t + s * 256;
    qs[e] = qb[e];
    int cq = e >> 7, w = e & 127;
    kts[w * 64 + cq] = kb[e];
  }
  __syncthreads();
  float* arow = attn + (size_t)bh * 16384;
  for (int r = 0; r < 32; ++r) {
    const int i = wv * 32 + r;
    const float* qrow = &qs[(i >> 1) * 128 + ((i & 1) << 6)];
    float elo = 0.f, ehi = 0.f;
#pragma unroll 16
    for (int c = 0; c < 64; ++c) {
      const float qv = qrow[c];
      elo = fmaf(qv, kts[(2 * c) * 64 + lane], elo);
      ehi = fmaf(qv, kts[(2 * c + 1) * 64 + lane], ehi);
    }
    float m = fmaxf(elo, ehi);
#pragma unroll
    for (int off = 32; off; off >>= 1) m = fmaxf(m, __shfl_xor(m, off));
    const float plo = __expf(elo - m), phi = __expf(ehi - m);
    float ssum = plo + phi;
#pragma unroll
    for (int off = 32; off; off >>= 1) ssum += __shfl_xor(ssum, off);
    const float inv = 1.0f / ssum;
    arow[i * 128 + lane]      = plo * inv;
    arow[i * 128 + 64 + lane] = phi * inv;
  }
}

// ---------------------------------------------------------------------------
// K3 (rewritten, MFMA): v conv1x1 tile + PV + epilogue.
// grid = BH*8 (c-tiles of 64), block = 256 (4 waves).
// Phase A: V[64 cout][128 j] = Wv_tile(64x512) @ X(512x128)   [mfma 16x16x32]
// Phase B: O[128 i][64 cout] = attn(128x128) @ V^T              [mfma 16x16x32]
// ---------------------------------------------------------------------------
__global__ __launch_bounds__(256) void out_kernel(
    const float* __restrict__ x, const float* __restrict__ Wv,
    const float* __restrict__ bv, const float* __restrict__ attn,
    const float* __restrict__ gamma, float* __restrict__ out) {
  // LDS (bytes):
  //  phase A: [0,20480)      xsT[2][128 j][40 cin] bf16  (pad 40 -> 80B rows,
  //                          16B-aligned, frag reads spread over all banks)
  //           [20480,30720)  wvs[2][64 cout][40 cin] bf16
  //  phase B: [0,34816)      attnb[128 i][136 j] bf16    (reuses phase-A space)
  //           [34816,52224)  vT[64 cout][136 j] bf16
  // total 52224 B -> 3 blocks/CU (12 waves/CU).
  __shared__ __align__(16) char smem[52224];
  __bf16* const xsT   = (__bf16*)smem;
  __bf16* const wvs   = (__bf16*)(smem + 20480);
  __bf16* const attnb = (__bf16*)smem;
  __bf16* const vT    = (__bf16*)(smem + 34816);

  const int t    = threadIdx.x;
  const int lane = t & 63;
  const int wid  = t >> 6;
  // XCD swizzle: blocks with equal L%8 round-robin to the same XCD; make each
  // XCD walk ct=0..7 of one bh consecutively -> 256KB x slab hits its L2.
  const int L  = blockIdx.x;
  const int g  = L >> 3;
  const int bh = ((L & 7) << 7) | (g >> 3);
  const int ct = g & 7;
  const int b  = bh >> 7, h = bh & 127;
  const float* const xbase = x + (size_t)b * C_ * HW_ + (size_t)h * W_;

  // ---------------- phase A ------------------------------------------------
  const int jj    = t & 127;   // staging: this thread's j column
  const int chalf = t >> 7;    // staging: cin half (0-15 / 16-31) of the chunk
  const int scout = t >> 2;    // staging: Wv row
  const int scg   = (t & 3) * 8;
  const int fr    = lane & 15; // mfma fragment lane row/col
  const int fg    = lane >> 4; // mfma fragment k-group (k = 8*fg + i)

  f32x4 acc[8];
#pragma unroll
  for (int jt = 0; jt < 8; ++jt)
#pragma unroll
    for (int r = 0; r < 4; ++r) acc[jt][r] = 0.f;

  float xr_[16], wr_[8];
  const float* const xcol = xbase + (size_t)chalf * 16 * HW_ + jj;
  const float* const wrow = Wv + (size_t)(ct * 64 + scout) * C_ + scg;

  // prologue: chunk 0 -> buf 0.  Global x reads: lane<->j (coalesced 256B);
  // each thread writes its 16 cins CONTIGUOUSLY -> transpose for free.
#pragma unroll
  for (int ci = 0; ci < 16; ++ci) xr_[ci] = xcol[(size_t)ci * HW_];
#pragma unroll
  for (int ci = 0; ci < 8; ++ci) wr_[ci] = wrow[ci];
  {
    __bf16* dx = xsT + jj * 40 + chalf * 16;
    bf16x8 p0, p1;
#pragma unroll
    for (int i = 0; i < 8; ++i) { p0[i] = (__bf16)xr_[i]; p1[i] = (__bf16)xr_[8 + i]; }
    *(bf16x8*)dx = p0; *(bf16x8*)(dx + 8) = p1;
    bf16x8 pw;
#pragma unroll
    for (int i = 0; i < 8; ++i) pw[i] = (__bf16)wr_[i];
    *(bf16x8*)(wvs + scout * 40 + scg) = pw;
  }

  for (int ch = 0; ch < 16; ++ch) {
    __syncthreads();               // staged chunk ch visible; prev buf free
    if (ch < 15) {                 // T14: issue next chunk loads before MFMAs
      const float* xc = xcol + (size_t)(ch + 1) * 32 * HW_;
#pragma unroll
      for (int ci = 0; ci < 16; ++ci) xr_[ci] = xc[(size_t)ci * HW_];
      const float* wc = wrow + (ch + 1) * 32;
#pragma unroll
      for (int ci = 0; ci < 8; ++ci) wr_[ci] = wc[ci];
    }
    const __bf16* xb = xsT + (ch & 1) * (128 * 40);
    const __bf16* wb = wvs + (ch & 1) * (64 * 40);
    // A = Wv[16 couts][32 cin], lane: m=fr, k=8*fg+i (k-contiguous b128)
    const bf16x8 a = *(const bf16x8*)(wb + (16 * wid + fr) * 40 + 8 * fg);
#pragma unroll
    for (int jt = 0; jt < 8; ++jt) {
      // B = X[32 cin][16 j], lane: n=fr(j), k=8*fg+i -> row of xsT
      const bf16x8 bb = *(const bf16x8*)(xb + (jt * 16 + fr) * 40 + 8 * fg);
      acc[jt] = __builtin_amdgcn_mfma_f32_16x16x32_bf16(a, bb, acc[jt], 0, 0, 0);
    }
    if (ch < 15) {                 // write staged chunk ch+1 (loads landed)
      __bf16* dx = xsT + ((ch + 1) & 1) * (128 * 40) + jj * 40 + chalf * 16;
      bf16x8 p0, p1;
#pragma unroll
      for (int i = 0; i < 8; ++i) { p0[i] = (__bf16)xr_[i]; p1[i] = (__bf16)xr_[8 + i]; }
      *(bf16x8*)dx = p0; *(bf16x8*)(dx + 8) = p1;
      bf16x8 pw;
#pragma unroll
      for (int i = 0; i < 8; ++i) pw[i] = (__bf16)wr_[i];
      *(bf16x8*)(wvs + ((ch + 1) & 1) * (64 * 40) + scout * 40 + scg) = pw;
    }
  }

  // D-frag (measured layout: col=lane&15, row=(lane>>4)*4+r) + bias -> vT
  {
    float bvv[4];
#pragma unroll
    for (int r = 0; r < 4; ++r) bvv[r] = bv[ct * 64 + 16 * wid + 4 * fg + r];
#pragma unroll
    for (int jt = 0; jt < 8; ++jt)
#pragma unroll
      for (int r = 0; r < 4; ++r)
        vT[(16 * wid + 4 * fg + r) * 136 + jt * 16 + fr] = (__bf16)(acc[jt][r] + bvv[r]);
  }
  __syncthreads();   // all phase-A LDS reads done -> attnb region reusable

  // stage attn: fp32 global (coalesced float4) -> bf16 LDS [128 i][136 j]
  const float* const ab = attn + (size_t)bh * 16384;
#pragma unroll 4
  for (int s = 0; s < 16; ++s) {
    const int fi = s * 256 + t;          // float4 index, 4096 total
    const int i = fi >> 5, j4 = fi & 31;
    const float4 av = *(const float4*)(ab + (size_t)fi * 4);
    bf16x4 pv;
    pv[0] = (__bf16)av.x; pv[1] = (__bf16)av.y; pv[2] = (__bf16)av.z; pv[3] = (__bf16)av.w;
    *(bf16x4*)(attnb + i * 136 + j4 * 4) = pv;
  }
  __syncthreads();

  // ---------------- phase B: wave wid owns couts [16*wid,16*wid+16) --------
  f32x4 o[8];
#pragma unroll
  for (int it = 0; it < 8; ++it)
#pragma unroll
    for (int r = 0; r < 4; ++r) o[it][r] = 0.f;

#pragma unroll
  for (int ks = 0; ks < 4; ++ks) {
    // B = v[cout][j]: lane n=fr(cout), k=j 8-contiguous in vT row
    const bf16x8 bb = *(const bf16x8*)(vT + (16 * wid + fr) * 136 + ks * 32 + 8 * fg);
#pragma unroll
    for (int it = 0; it < 8; ++it) {
      // A = attn[i][j]: lane m=fr(i), k=j 8-contiguous
      const bf16x8 aa = *(const bf16x8*)(attnb + (it * 16 + fr) * 136 + ks * 32 + 8 * fg);
      o[it] = __builtin_amdgcn_mfma_f32_16x16x32_bf16(aa, bb, o[it], 0, 0, 0);
    }
  }

  // epilogue: out = gamma * O + x   (r=0..3 -> 4 consecutive i -> float4;
  // lanes l, l+16, l+32, l+48 merge into full 64B lines per cout row)
  const float gam = gamma[0];
  const size_t cb = ((size_t)b * C_ + ct * 64 + 16 * wid + fr) * HW_ + (size_t)h * W_;
#pragma unroll
  for (int it = 0; it < 8; ++it) {
    const size_t off = cb + it * 16 + 4 * fg;
    const float4 xv = *(const float4*)(x + off);
    float4 ov;
    ov.x = fmaf(gam, o[it][0], xv.x);
    ov.y = fmaf(gam, o[it][1], xv.y);
    ov.z = fmaf(gam, o[it][2], xv.z);
    ov.w = fmaf(gam, o[it][3], xv.w);
    *(float4*)(out + off) = ov;
  }
}

// ---------------------------------------------------------------------------
extern "C" void kernel_launch(void* const* d_in, const int* in_sizes, int n_in,
                              void* d_out, int out_size, void* d_ws, size_t ws_size,
                              hipStream_t stream) {
  const float* x     = (const float*)d_in[0];
  const float* Wq    = (const float*)d_in[1];
  const float* bq    = (const float*)d_in[2];
  const float* Wk    = (const float*)d_in[3];
  const float* bk    = (const float*)d_in[4];
  const float* Wv    = (const float*)d_in[5];
  const float* bv    = (const float*)d_in[6];
  const float* gamma = (const float*)d_in[7];
  float* out = (float*)d_out;

  // q,k scratch inside d_out (16.8M floats of 67.1M); K3 overwrites everything.
  float* qbuf = out;
  float* kbuf = out + (size_t)BH_ * CQ_ * W_;
  float* attn = (float*)d_ws;  // 64 MiB

  qk_kernel<<<BH_, 256, 0, stream>>>(x, Wq, bq, Wk, bk, qbuf, kbuf);
  attn_kernel<<<BH_, 256, 0, stream>>>(qbuf, kbuf, attn);
  out_kernel<<<BH_ * 8, 256, 0, stream>>>(x, Wv, bv, attn, gamma, out);
}

// Round 2
// 752.179 us; speedup vs baseline: 3.0048x; 1.5007x over previous
//
#include <hip/hip_runtime.h>
#include <hip/hip_bf16.h>

#define B_   8
#define C_   512
#define H_   128
#define W_   128
#define CQ_  64
#define BH_  (B_ * H_)
#define HW_  (H_ * W_)

typedef __bf16 bf16x8 __attribute__((ext_vector_type(8)));
typedef __bf16 bf16x4 __attribute__((ext_vector_type(4)));
typedef float  f32x4  __attribute__((ext_vector_type(4)));

__device__ __forceinline__ void split8(const float* v, bf16x8& h, bf16x8& l) {
#pragma unroll
  for (int i = 0; i < 8; ++i) {
    const __bf16 hv = (__bf16)v[i];
    h[i] = hv;
    l[i] = (__bf16)(v[i] - (float)hv);
  }
}

// ---------------------------------------------------------------------------
// K1 (MFMA): q,k conv1x1.  grid = BH (1024), block = 256 (4 waves).
// M=128 rows ([Wq;Wk]), N=128 w, K=512 cin.  hi/lo bf16 split for ~fp32 acc.
// Wave wid owns M rows [32*wid, 32*wid+32): wid 0,1 -> q, wid 2,3 -> k.
// ---------------------------------------------------------------------------
__global__ __launch_bounds__(256) void qk_kernel(
    const float* __restrict__ x, const float* __restrict__ Wq,
    const float* __restrict__ bq, const float* __restrict__ Wk,
    const float* __restrict__ bk, float* __restrict__ qout,
    float* __restrict__ kout) {
  __shared__ __align__(16) __bf16 xh[128 * 40];  // [j][cin] pad 40
  __shared__ __align__(16) __bf16 xl[128 * 40];
  __shared__ __align__(16) __bf16 wh[128 * 40];  // [row][cin] rows: 0-63 Wq, 64-127 Wk
  __shared__ __align__(16) __bf16 wl[128 * 40];

  const int t    = threadIdx.x;
  const int lane = t & 63, wid = t >> 6;
  const int fr   = lane & 15, fg = lane >> 4;
  const int bh   = blockIdx.x;
  const int b    = bh >> 7, h = bh & 127;

  // staging assignments
  const int jj = t & 127, chalf = t >> 7;         // x: column j, cin half
  const int srow = t >> 1, sc16 = (t & 1) * 16;   // W: row, cin 16-group

  const float* const xcol =
      x + (size_t)b * C_ * HW_ + (size_t)h * W_ + (size_t)chalf * 16 * HW_ + jj;
  const float* const wrow =
      (srow < 64 ? Wq + (size_t)srow * C_ : Wk + (size_t)(srow - 64) * C_) + sc16;

  f32x4 acc[2][8];
#pragma unroll
  for (int mt = 0; mt < 2; ++mt)
#pragma unroll
    for (int jt = 0; jt < 8; ++jt)
#pragma unroll
      for (int r = 0; r < 4; ++r) acc[mt][jt][r] = 0.f;

  float xr_[16], wr_[16];
#pragma unroll
  for (int ci = 0; ci < 16; ++ci) xr_[ci] = xcol[(size_t)ci * HW_];
#pragma unroll
  for (int ci = 0; ci < 16; ++ci) wr_[ci] = wrow[ci];

  for (int ch = 0; ch < 16; ++ch) {
    __syncthreads();  // previous chunk's MFMA LDS reads complete
    {
      bf16x8 h0, l0, h1, l1;
      split8(xr_, h0, l0); split8(xr_ + 8, h1, l1);
      __bf16* dx = xh + jj * 40 + chalf * 16;
      __bf16* dl = xl + jj * 40 + chalf * 16;
      *(bf16x8*)dx = h0; *(bf16x8*)(dx + 8) = h1;
      *(bf16x8*)dl = l0; *(bf16x8*)(dl + 8) = l1;
      split8(wr_, h0, l0); split8(wr_ + 8, h1, l1);
      __bf16* dw = wh + srow * 40 + sc16;
      __bf16* dwl = wl + srow * 40 + sc16;
      *(bf16x8*)dw = h0; *(bf16x8*)(dw + 8) = h1;
      *(bf16x8*)dwl = l0; *(bf16x8*)(dwl + 8) = l1;
    }
    __syncthreads();  // staged chunk visible
    if (ch < 15) {    // T14: issue next chunk's global loads before MFMAs
      const float* xc = xcol + (size_t)(ch + 1) * 32 * HW_;
#pragma unroll
      for (int ci = 0; ci < 16; ++ci) xr_[ci] = xc[(size_t)ci * HW_];
      const float* wc = wrow + (ch + 1) * 32;
#pragma unroll
      for (int ci = 0; ci < 16; ++ci) wr_[ci] = wc[ci];
    }
    bf16x8 ah[2], al[2];
#pragma unroll
    for (int mt = 0; mt < 2; ++mt) {
      const int mrow = 32 * wid + 16 * mt + fr;
      ah[mt] = *(const bf16x8*)(wh + mrow * 40 + 8 * fg);
      al[mt] = *(const bf16x8*)(wl + mrow * 40 + 8 * fg);
    }
#pragma unroll
    for (int jt = 0; jt < 8; ++jt) {
      const bf16x8 bhv = *(const bf16x8*)(xh + (jt * 16 + fr) * 40 + 8 * fg);
      const bf16x8 blv = *(const bf16x8*)(xl + (jt * 16 + fr) * 40 + 8 * fg);
#pragma unroll
      for (int mt = 0; mt < 2; ++mt) {
        acc[mt][jt] = __builtin_amdgcn_mfma_f32_16x16x32_bf16(ah[mt], bhv, acc[mt][jt], 0, 0, 0);
        acc[mt][jt] = __builtin_amdgcn_mfma_f32_16x16x32_bf16(ah[mt], blv, acc[mt][jt], 0, 0, 0);
        acc[mt][jt] = __builtin_amdgcn_mfma_f32_16x16x32_bf16(al[mt], bhv, acc[mt][jt], 0, 0, 0);
      }
    }
  }

  // epilogue: D col = fr (w), row = 4*fg + r.  wid 0,1 -> q rows; 2,3 -> k.
  float* const obase = (wid < 2 ? qout : kout) + (size_t)bh * CQ_ * W_;
  const float* const bias = (wid < 2 ? bq : bk);
  const int rb = 32 * (wid & 1);
#pragma unroll
  for (int mt = 0; mt < 2; ++mt)
#pragma unroll
    for (int r = 0; r < 4; ++r) {
      const int row = rb + 16 * mt + 4 * fg + r;
      const float bb = bias[row];
      float* orow = obase + row * W_;
#pragma unroll
      for (int jt = 0; jt < 8; ++jt) orow[jt * 16 + fr] = acc[mt][jt][r] + bb;
    }
}

// ---------------------------------------------------------------------------
// K2 (MFMA): energy + softmax.  grid = BH, block = 256 (4 waves).
// E[i][j] = sum_c Q'[i][c] * K'[c][j],  Q'[i][c] = q_mem[64i+c] (linear view),
// K'[c][j] = k_mem[(j&63)*128 + 2c + (j>>6)].  hi/lo split.  attn out bf16.
// ---------------------------------------------------------------------------
__global__ __launch_bounds__(256) void attn_kernel(
    const float* __restrict__ qin, const float* __restrict__ kin,
    __bf16* __restrict__ attn) {
  __shared__ __align__(16) __bf16 qh[128 * 72];  // [i][c] pad 72
  __shared__ __align__(16) __bf16 ql[128 * 72];
  __shared__ __align__(16) __bf16 kh[128 * 72];  // [j][c] pad 72
  __shared__ __align__(16) __bf16 kl[128 * 72];

  const int t    = threadIdx.x;
  const int lane = t & 63, wid = t >> 6;
  const int fr   = lane & 15, fg = lane >> 4;
  const int bh   = blockIdx.x;
  const float* const qb = qin + (size_t)bh * 8192;
  const float* const kb = kin + (size_t)bh * 8192;

  // stage Q' and K'T (hi/lo)
#pragma unroll
  for (int s = 0; s < 4; ++s) {
    const int e = (s * 256 + t) * 8;
    // Q': linear 8 floats -> row i = e>>6, cols c = e&63 .. +7
    {
      float v[8];
      *(float4*)&v[0] = *(const float4*)(qb + e);
      *(float4*)&v[4] = *(const float4*)(qb + e + 4);
      bf16x8 hv, lv;
      split8(v, hv, lv);
      const int i = e >> 6, c = e & 63;
      *(bf16x8*)(qh + i * 72 + c) = hv;
      *(bf16x8*)(ql + i * 72 + c) = lv;
    }
    // K': k_mem[cq*128 + w] -> K'T[j = cq + 64*(w&1)][c = w>>1]
    {
      float v[8];
      *(float4*)&v[0] = *(const float4*)(kb + e);
      *(float4*)&v[4] = *(const float4*)(kb + e + 4);
      const int cq = e >> 7, w0 = e & 127;
      bf16x4 he, ho, le, lo_;
#pragma unroll
      for (int m = 0; m < 4; ++m) {
        const float ve = v[2 * m], vo = v[2 * m + 1];
        const __bf16 hev = (__bf16)ve, hov = (__bf16)vo;
        he[m] = hev; le[m] = (__bf16)(ve - (float)hev);
        ho[m] = hov; lo_[m] = (__bf16)(vo - (float)hov);
      }
      const int c0 = w0 >> 1;
      *(bf16x4*)(kh + cq * 72 + c0)        = he;
      *(bf16x4*)(kh + (cq + 64) * 72 + c0) = ho;
      *(bf16x4*)(kl + cq * 72 + c0)        = le;
      *(bf16x4*)(kl + (cq + 64) * 72 + c0) = lo_;
    }
  }
  __syncthreads();

  f32x4 e_[2][8];
#pragma unroll
  for (int mt = 0; mt < 2; ++mt)
#pragma unroll
    for (int jt = 0; jt < 8; ++jt)
#pragma unroll
      for (int r = 0; r < 4; ++r) e_[mt][jt][r] = 0.f;

#pragma unroll
  for (int ks = 0; ks < 2; ++ks) {
    bf16x8 ah[2], al[2];
#pragma unroll
    for (int mt = 0; mt < 2; ++mt) {
      const int row = 32 * wid + 16 * mt + fr;
      ah[mt] = *(const bf16x8*)(qh + row * 72 + ks * 32 + 8 * fg);
      al[mt] = *(const bf16x8*)(ql + row * 72 + ks * 32 + 8 * fg);
    }
#pragma unroll
    for (int jt = 0; jt < 8; ++jt) {
      const int row = jt * 16 + fr;
      const bf16x8 bhv = *(const bf16x8*)(kh + row * 72 + ks * 32 + 8 * fg);
      const bf16x8 blv = *(const bf16x8*)(kl + row * 72 + ks * 32 + 8 * fg);
#pragma unroll
      for (int mt = 0; mt < 2; ++mt) {
        e_[mt][jt] = __builtin_amdgcn_mfma_f32_16x16x32_bf16(ah[mt], bhv, e_[mt][jt], 0, 0, 0);
        e_[mt][jt] = __builtin_amdgcn_mfma_f32_16x16x32_bf16(ah[mt], blv, e_[mt][jt], 0, 0, 0);
        e_[mt][jt] = __builtin_amdgcn_mfma_f32_16x16x32_bf16(al[mt], bhv, e_[mt][jt], 0, 0, 0);
      }
    }
  }

  // softmax over j (128) per row i = 32*wid + 16*mt + 4*fg + r.
  // Lanes sharing fg (16 lanes, fr=0..15) hold one row -> shfl_xor 1,2,4,8.
  __bf16* const abase = attn + (size_t)bh * 16384;
#pragma unroll
  for (int mt = 0; mt < 2; ++mt)
#pragma unroll
    for (int r = 0; r < 4; ++r) {
      float mx = e_[mt][0][r];
#pragma unroll
      for (int jt = 1; jt < 8; ++jt) mx = fmaxf(mx, e_[mt][jt][r]);
#pragma unroll
      for (int off = 1; off < 16; off <<= 1) mx = fmaxf(mx, __shfl_xor(mx, off));
      float p[8], ssum = 0.f;
#pragma unroll
      for (int jt = 0; jt < 8; ++jt) { p[jt] = __expf(e_[mt][jt][r] - mx); ssum += p[jt]; }
#pragma unroll
      for (int off = 1; off < 16; off <<= 1) ssum += __shfl_xor(ssum, off);
      const float inv = 1.0f / ssum;
      const int row = 32 * wid + 16 * mt + 4 * fg + r;
      __bf16* arow = abase + row * 128;
#pragma unroll
      for (int jt = 0; jt < 8; ++jt) arow[jt * 16 + fr] = (__bf16)(p[jt] * inv);
    }
}

// ---------------------------------------------------------------------------
// K3 (MFMA): v conv1x1 tile + PV + epilogue.  grid = BH*8, block = 256.
// (unchanged except attn is now bf16 -> staging is a straight copy)
// ---------------------------------------------------------------------------
__global__ __launch_bounds__(256) void out_kernel(
    const float* __restrict__ x, const float* __restrict__ Wv,
    const float* __restrict__ bv, const __bf16* __restrict__ attn,
    const float* __restrict__ gamma, float* __restrict__ out) {
  __shared__ __align__(16) char smem[52224];
  __bf16* const xsT   = (__bf16*)smem;                 // [2][128 j][40 cin]
  __bf16* const wvs   = (__bf16*)(smem + 20480);       // [2][64 cout][40 cin]
  __bf16* const attnb = (__bf16*)smem;                 // [128 i][136 j]
  __bf16* const vT    = (__bf16*)(smem + 34816);       // [64 cout][136 j]

  const int t    = threadIdx.x;
  const int lane = t & 63;
  const int wid  = t >> 6;
  const int L  = blockIdx.x;
  const int g  = L >> 3;
  const int bh = ((L & 7) << 7) | (g >> 3);
  const int ct = g & 7;
  const int b  = bh >> 7, h = bh & 127;
  const float* const xbase = x + (size_t)b * C_ * HW_ + (size_t)h * W_;

  const int jj    = t & 127;
  const int chalf = t >> 7;
  const int scout = t >> 2;
  const int scg   = (t & 3) * 8;
  const int fr    = lane & 15;
  const int fg    = lane >> 4;

  f32x4 acc[8];
#pragma unroll
  for (int jt = 0; jt < 8; ++jt)
#pragma unroll
    for (int r = 0; r < 4; ++r) acc[jt][r] = 0.f;

  float xr_[16], wr_[8];
  const float* const xcol = xbase + (size_t)chalf * 16 * HW_ + jj;
  const float* const wrow = Wv + (size_t)(ct * 64 + scout) * C_ + scg;

#pragma unroll
  for (int ci = 0; ci < 16; ++ci) xr_[ci] = xcol[(size_t)ci * HW_];
#pragma unroll
  for (int ci = 0; ci < 8; ++ci) wr_[ci] = wrow[ci];
  {
    __bf16* dx = xsT + jj * 40 + chalf * 16;
    bf16x8 p0, p1;
#pragma unroll
    for (int i = 0; i < 8; ++i) { p0[i] = (__bf16)xr_[i]; p1[i] = (__bf16)xr_[8 + i]; }
    *(bf16x8*)dx = p0; *(bf16x8*)(dx + 8) = p1;
    bf16x8 pw;
#pragma unroll
    for (int i = 0; i < 8; ++i) pw[i] = (__bf16)wr_[i];
    *(bf16x8*)(wvs + scout * 40 + scg) = pw;
  }

  for (int ch = 0; ch < 16; ++ch) {
    __syncthreads();
    if (ch < 15) {
      const float* xc = xcol + (size_t)(ch + 1) * 32 * HW_;
#pragma unroll
      for (int ci = 0; ci < 16; ++ci) xr_[ci] = xc[(size_t)ci * HW_];
      const float* wc = wrow + (ch + 1) * 32;
#pragma unroll
      for (int ci = 0; ci < 8; ++ci) wr_[ci] = wc[ci];
    }
    const __bf16* xb = xsT + (ch & 1) * (128 * 40);
    const __bf16* wb = wvs + (ch & 1) * (64 * 40);
    const bf16x8 a = *(const bf16x8*)(wb + (16 * wid + fr) * 40 + 8 * fg);
#pragma unroll
    for (int jt = 0; jt < 8; ++jt) {
      const bf16x8 bb = *(const bf16x8*)(xb + (jt * 16 + fr) * 40 + 8 * fg);
      acc[jt] = __builtin_amdgcn_mfma_f32_16x16x32_bf16(a, bb, acc[jt], 0, 0, 0);
    }
    if (ch < 15) {
      __bf16* dx = xsT + ((ch + 1) & 1) * (128 * 40) + jj * 40 + chalf * 16;
      bf16x8 p0, p1;
#pragma unroll
      for (int i = 0; i < 8; ++i) { p0[i] = (__bf16)xr_[i]; p1[i] = (__bf16)xr_[8 + i]; }
      *(bf16x8*)dx = p0; *(bf16x8*)(dx + 8) = p1;
      bf16x8 pw;
#pragma unroll
      for (int i = 0; i < 8; ++i) pw[i] = (__bf16)wr_[i];
      *(bf16x8*)(wvs + ((ch + 1) & 1) * (64 * 40) + scout * 40 + scg) = pw;
    }
  }

  {
    float bvv[4];
#pragma unroll
    for (int r = 0; r < 4; ++r) bvv[r] = bv[ct * 64 + 16 * wid + 4 * fg + r];
#pragma unroll
    for (int jt = 0; jt < 8; ++jt)
#pragma unroll
      for (int r = 0; r < 4; ++r)
        vT[(16 * wid + 4 * fg + r) * 136 + jt * 16 + fr] = (__bf16)(acc[jt][r] + bvv[r]);
  }
  __syncthreads();

  // stage attn bf16 -> LDS [128 i][136 j] (straight uint4 copy)
  const uint4* const ab = (const uint4*)(attn + (size_t)bh * 16384);
#pragma unroll
  for (int s = 0; s < 8; ++s) {
    const int e = s * 256 + t;      // uint4 index over 2048 (= 8 bf16 each)
    const int i = e >> 4, j8 = e & 15;
    *(uint4*)(attnb + i * 136 + j8 * 8) = ab[e];
  }
  __syncthreads();

  f32x4 o[8];
#pragma unroll
  for (int it = 0; it < 8; ++it)
#pragma unroll
    for (int r = 0; r < 4; ++r) o[it][r] = 0.f;

#pragma unroll
  for (int ks = 0; ks < 4; ++ks) {
    const bf16x8 bb = *(const bf16x8*)(vT + (16 * wid + fr) * 136 + ks * 32 + 8 * fg);
#pragma unroll
    for (int it = 0; it < 8; ++it) {
      const bf16x8 aa = *(const bf16x8*)(attnb + (it * 16 + fr) * 136 + ks * 32 + 8 * fg);
      o[it] = __builtin_amdgcn_mfma_f32_16x16x32_bf16(aa, bb, o[it], 0, 0, 0);
    }
  }

  const float gam = gamma[0];
  const size_t cb = ((size_t)b * C_ + ct * 64 + 16 * wid + fr) * HW_ + (size_t)h * W_;
#pragma unroll
  for (int it = 0; it < 8; ++it) {
    const size_t off = cb + it * 16 + 4 * fg;
    const float4 xv = *(const float4*)(x + off);
    float4 ov;
    ov.x = fmaf(gam, o[it][0], xv.x);
    ov.y = fmaf(gam, o[it][1], xv.y);
    ov.z = fmaf(gam, o[it][2], xv.z);
    ov.w = fmaf(gam, o[it][3], xv.w);
    *(float4*)(out + off) = ov;
  }
}

// ---------------------------------------------------------------------------
extern "C" void kernel_launch(void* const* d_in, const int* in_sizes, int n_in,
                              void* d_out, int out_size, void* d_ws, size_t ws_size,
                              hipStream_t stream) {
  const float* x     = (const float*)d_in[0];
  const float* Wq    = (const float*)d_in[1];
  const float* bq    = (const float*)d_in[2];
  const float* Wk    = (const float*)d_in[3];
  const float* bk    = (const float*)d_in[4];
  const float* Wv    = (const float*)d_in[5];
  const float* bv    = (const float*)d_in[6];
  const float* gamma = (const float*)d_in[7];
  float* out = (float*)d_out;

  // q,k scratch inside d_out (16.8M floats of 67.1M); K3 overwrites everything.
  float* qbuf = out;
  float* kbuf = out + (size_t)BH_ * CQ_ * W_;
  __bf16* attn = (__bf16*)d_ws;  // 32 MiB bf16 of the 64 MiB workspace

  qk_kernel<<<BH_, 256, 0, stream>>>(x, Wq, bq, Wk, bk, qbuf, kbuf);
  attn_kernel<<<BH_, 256, 0, stream>>>(qbuf, kbuf, attn);
  out_kernel<<<BH_ * 8, 256, 0, stream>>>(x, Wv, bv, attn, gamma, out);
}